// Round 12
// baseline (124.223 us; speedup 1.0000x reference)
//
#include <hip/hip_runtime.h>
#include <hip/hip_bf16.h>

// Relative (Transformer-XL) multi-head attention, MI355X gfx950.
// B=8, T=1024, H=8, d=64, D_MODEL=512, W=2047. Output f32.
//
// Round 12 = R11 + two changes:
//  - attn: prob-region XOR swizzle col'=(fn^g)*16+l15 (write) /
//    granule^(l15>>2) (read) -> kills the 4-way bank conflict on the 16
//    scalar prob writes (the 16g mod 32 fold). Zero extra instructions.
//  - QV buffer eliminated: attn computes aqv = aqu + (v-u) in registers;
//    qkv epilogue writes Q once (QU only). -4MB write, -4MB read.

typedef __attribute__((ext_vector_type(8))) short short8;
typedef __attribute__((ext_vector_type(4))) float float4v;
typedef __fp16 h2v __attribute__((ext_vector_type(2)));

__device__ __forceinline__ unsigned short f2bf(float f) {
  union { float f; unsigned u; } x; x.f = f;
  unsigned r = x.u + 0x7FFFu + ((x.u >> 16) & 1u);
  return (unsigned short)(r >> 16);
}
__device__ __forceinline__ float bf2f(unsigned short b) {
  union { unsigned u; float f; } x; x.u = ((unsigned)b) << 16;
  return x.f;
}
__device__ __forceinline__ int pk2h(float a, float b) {
  union { h2v h; int i; } c; c.h = __builtin_amdgcn_cvt_pkrtz(a, b);
  return c.i;
}
__device__ __forceinline__ float h_lo(int w) {
  union { int i; h2v h; } c; c.i = w; return (float)c.h.x;
}
__device__ __forceinline__ float h_hi(int w) {
  union { int i; h2v h; } c; c.i = w; return (float)c.h.y;
}

// ---------- conversion kernels ----------
__global__ void cvt_bf16_kernel(const float* __restrict__ in,
                                unsigned short* __restrict__ out, int n4) {
  int i = blockIdx.x * blockDim.x + threadIdx.x;
  if (i < n4) {
    float4 f = ((const float4*)in)[i];
    ushort4 r;
    r.x = f2bf(f.x); r.y = f2bf(f.y); r.z = f2bf(f.z); r.w = f2bf(f.w);
    ((ushort4*)out)[i] = r;
  }
}

// 5x 512x512 transpose+cvt, LDS-tiled (coalesced loads AND stores)
__global__ void transpose_cvt5_kernel(const float* __restrict__ Wq,
                                      const float* __restrict__ Wk,
                                      const float* __restrict__ Wv,
                                      const float* __restrict__ Wp,
                                      const float* __restrict__ Wo,
                                      unsigned short* __restrict__ dst) {
  __shared__ float T[64][65];
  int y = blockIdx.y;
  const float* w = (y == 0) ? Wq : (y == 1) ? Wk : (y == 2) ? Wv : (y == 3) ? Wp : Wo;
  unsigned short* wt = dst + (size_t)y * 262144;
  int bx = blockIdx.x;                       // 64 tiles of 64x64
  int r0 = (bx >> 3) * 64, c0 = (bx & 7) * 64;
  int tid = threadIdx.x;
  int row = tid >> 2, cq = (tid & 3) * 16;
  const float* src = w + (size_t)(r0 + row) * 512 + c0 + cq;
#pragma unroll
  for (int j = 0; j < 4; ++j) {
    float4 f = *(const float4*)(src + j * 4);
    T[row][cq + j * 4 + 0] = f.x; T[row][cq + j * 4 + 1] = f.y;
    T[row][cq + j * 4 + 2] = f.z; T[row][cq + j * 4 + 3] = f.w;
  }
  __syncthreads();
  unsigned short tmp[16];
#pragma unroll
  for (int j = 0; j < 16; ++j) tmp[j] = f2bf(T[cq + j][row]);
  unsigned short* op = wt + (size_t)(c0 + row) * 512 + r0 + cq;
  *(uint4*)op       = *(uint4*)tmp;
  *(uint4*)(op + 8) = *(uint4*)(tmp + 8);
}

// ---------- 128x128-tile projection GEMM (QKV + pos) ----------
// nt 0..3: Q -> QU (q+bq+u); nt 4..7: K; nt 8..11: V -> Vt transposed;
// nt 12: pos projection (A=peb, B=wpt, C=pb; mt encodes pmt/pnt).
__global__ __launch_bounds__(256, 2) void qkv_gemm128(
    const unsigned short* __restrict__ A,
    const unsigned short* __restrict__ Bt,
    const float* __restrict__ bq,
    const float* __restrict__ uvec,
    unsigned short* __restrict__ QU,
    unsigned short* __restrict__ Kb, unsigned short* __restrict__ Vt,
    const unsigned short* __restrict__ Pe,   // peb (2048x512)
    const unsigned short* __restrict__ Wpt,  // Wp^T
    unsigned short* __restrict__ Pb) {       // pos out (2048x512)
  __shared__ __align__(16) unsigned short lds[2 * 128 * 72];
  unsigned short (*As)[72] = (unsigned short(*)[72])lds;
  unsigned short (*Bs)[72] = (unsigned short(*)[72])(lds + 128 * 72);
  int mt = blockIdx.x, nt = blockIdx.y;
  int tid = threadIdx.x;
  int lane = tid & 63, wave = tid >> 6;
  int l15 = lane & 15, g = lane >> 4;
  int wr = (wave >> 1) << 6, wc = (wave & 1) << 6;
  int sr = tid >> 1, sc = (tid & 1) << 5;

  const unsigned short* Ap;
  const unsigned short* Bp;
  if (nt < 12) {
    Ap = A + (size_t)(mt * 128 + sr) * 512 + sc;
    Bp = Bt + (size_t)(nt * 128 + sr) * 512 + sc;
  } else {
    Ap = Pe + (size_t)((mt & 15) * 128 + sr) * 512 + sc;
    Bp = Wpt + (size_t)((mt >> 4) * 128 + sr) * 512 + sc;
  }

  uint4 a0 = *(const uint4*)Ap,        a1 = *(const uint4*)(Ap + 8);
  uint4 a2 = *(const uint4*)(Ap + 16), a3 = *(const uint4*)(Ap + 24);
  uint4 b0 = *(const uint4*)Bp,        b1 = *(const uint4*)(Bp + 8);
  uint4 b2 = *(const uint4*)(Bp + 16), b3 = *(const uint4*)(Bp + 24);

  float4v acc[4][4] = {};
  for (int kt = 0; kt < 8; ++kt) {
    *(uint4*)&As[sr][sc]      = a0; *(uint4*)&As[sr][sc + 8]  = a1;
    *(uint4*)&As[sr][sc + 16] = a2; *(uint4*)&As[sr][sc + 24] = a3;
    *(uint4*)&Bs[sr][sc]      = b0; *(uint4*)&Bs[sr][sc + 8]  = b1;
    *(uint4*)&Bs[sr][sc + 16] = b2; *(uint4*)&Bs[sr][sc + 24] = b3;
    __syncthreads();
    if (kt < 7) {
      const unsigned short* ap = Ap + (kt + 1) * 64;
      a0 = *(const uint4*)ap;        a1 = *(const uint4*)(ap + 8);
      a2 = *(const uint4*)(ap + 16); a3 = *(const uint4*)(ap + 24);
      const unsigned short* bp = Bp + (kt + 1) * 64;
      b0 = *(const uint4*)bp;        b1 = *(const uint4*)(bp + 8);
      b2 = *(const uint4*)(bp + 16); b3 = *(const uint4*)(bp + 24);
    }
#pragma unroll
    for (int ks = 0; ks < 2; ++ks) {
      short8 af[4], bf[4];
#pragma unroll
      for (int fm = 0; fm < 4; ++fm)
        af[fm] = *(const short8*)&As[wr + fm * 16 + l15][ks * 32 + g * 8];
#pragma unroll
      for (int fn = 0; fn < 4; ++fn)
        bf[fn] = *(const short8*)&Bs[wc + fn * 16 + l15][ks * 32 + g * 8];
#pragma unroll
      for (int fm = 0; fm < 4; ++fm)
#pragma unroll
        for (int fn = 0; fn < 4; ++fn)
          acc[fm][fn] = __builtin_amdgcn_mfma_f32_16x16x32_bf16(
              af[fm], bf[fn], acc[fm][fn], 0, 0, 0);
    }
    if (kt < 7) __syncthreads();
  }

  if (nt < 4) {
#pragma unroll
    for (int fn = 0; fn < 4; ++fn) {
      int col = nt * 128 + wc + fn * 16 + l15;
      float bs = bq[col] + uvec[col];
#pragma unroll
      for (int fm = 0; fm < 4; ++fm) {
        int row = mt * 128 + wr + fm * 16 + 4 * g;
#pragma unroll
        for (int r = 0; r < 4; ++r)
          QU[(size_t)(row + r) * 512 + col] = f2bf(acc[fm][fn][r] + bs);
      }
    }
  } else if (nt < 8) {
#pragma unroll
    for (int fn = 0; fn < 4; ++fn) {
      int col = (nt - 4) * 128 + wc + fn * 16 + l15;
#pragma unroll
      for (int fm = 0; fm < 4; ++fm) {
        int row = mt * 128 + wr + fm * 16 + 4 * g;
#pragma unroll
        for (int r = 0; r < 4; ++r)
          Kb[(size_t)(row + r) * 512 + col] = f2bf(acc[fm][fn][r]);
      }
    }
  } else if (nt < 12) {
    // V: transpose 128x128 tile through LDS, write Vt[b][h][d][s]
    __syncthreads();
    unsigned short (*T)[136] = (unsigned short(*)[136])lds;
#pragma unroll
    for (int fm = 0; fm < 4; ++fm)
#pragma unroll
      for (int fn = 0; fn < 4; ++fn)
#pragma unroll
        for (int r = 0; r < 4; ++r)
          T[wc + fn * 16 + l15][wr + fm * 16 + 4 * g + r] = f2bf(acc[fm][fn][r]);
    __syncthreads();
    int c2 = tid >> 1, sh = (tid & 1) << 6;
    int gcol = (nt - 8) * 128 + c2;
    int bb = mt >> 3, s0 = (mt & 7) * 128;
    unsigned short* op = Vt +
        ((size_t)((bb * 8 + (gcol >> 6)) * 64 + (gcol & 63))) * 1024 + s0 + sh;
#pragma unroll
    for (int j = 0; j < 8; ++j)
      *(uint4*)(op + j * 8) = *(uint4*)&T[c2][sh + j * 8];
  } else {
#pragma unroll
    for (int fn = 0; fn < 4; ++fn) {
      int col = (mt >> 4) * 128 + wc + fn * 16 + l15;
#pragma unroll
      for (int fm = 0; fm < 4; ++fm) {
        int row = (mt & 15) * 128 + wr + fm * 16 + 4 * g;
#pragma unroll
        for (int r = 0; r < 4; ++r)
          Pb[(size_t)(row + r) * 512 + col] = f2bf(acc[fm][fn][r]);
      }
    }
  }
}

// ---------- 128x128-tile GEMM, f32 out + bias (out projection) ----------
__global__ __launch_bounds__(256, 2) void gemm128f(
    const unsigned short* __restrict__ A,
    const unsigned short* __restrict__ Bt,
    const float* __restrict__ bias,
    float* __restrict__ Cf) {
  __shared__ __align__(16) unsigned short lds[2 * 128 * 72];
  unsigned short (*As)[72] = (unsigned short(*)[72])lds;
  unsigned short (*Bs)[72] = (unsigned short(*)[72])(lds + 128 * 72);
  int mt = blockIdx.x, nt = blockIdx.y;
  int tid = threadIdx.x;
  int lane = tid & 63, wave = tid >> 6;
  int l15 = lane & 15, g = lane >> 4;
  int wr = (wave >> 1) << 6, wc = (wave & 1) << 6;
  int sr = tid >> 1, sc = (tid & 1) << 5;

  const unsigned short* Ap = A + (size_t)(mt * 128 + sr) * 512 + sc;
  const unsigned short* Bp = Bt + (size_t)(nt * 128 + sr) * 512 + sc;

  uint4 a0 = *(const uint4*)Ap,        a1 = *(const uint4*)(Ap + 8);
  uint4 a2 = *(const uint4*)(Ap + 16), a3 = *(const uint4*)(Ap + 24);
  uint4 b0 = *(const uint4*)Bp,        b1 = *(const uint4*)(Bp + 8);
  uint4 b2 = *(const uint4*)(Bp + 16), b3 = *(const uint4*)(Bp + 24);

  float4v acc[4][4] = {};
  for (int kt = 0; kt < 8; ++kt) {
    *(uint4*)&As[sr][sc]      = a0; *(uint4*)&As[sr][sc + 8]  = a1;
    *(uint4*)&As[sr][sc + 16] = a2; *(uint4*)&As[sr][sc + 24] = a3;
    *(uint4*)&Bs[sr][sc]      = b0; *(uint4*)&Bs[sr][sc + 8]  = b1;
    *(uint4*)&Bs[sr][sc + 16] = b2; *(uint4*)&Bs[sr][sc + 24] = b3;
    __syncthreads();
    if (kt < 7) {
      const unsigned short* ap = Ap + (kt + 1) * 64;
      a0 = *(const uint4*)ap;        a1 = *(const uint4*)(ap + 8);
      a2 = *(const uint4*)(ap + 16); a3 = *(const uint4*)(ap + 24);
      const unsigned short* bp = Bp + (kt + 1) * 64;
      b0 = *(const uint4*)bp;        b1 = *(const uint4*)(bp + 8);
      b2 = *(const uint4*)(bp + 16); b3 = *(const uint4*)(bp + 24);
    }
#pragma unroll
    for (int ks = 0; ks < 2; ++ks) {
      short8 af[4], bf[4];
#pragma unroll
      for (int fm = 0; fm < 4; ++fm)
        af[fm] = *(const short8*)&As[wr + fm * 16 + l15][ks * 32 + g * 8];
#pragma unroll
      for (int fn = 0; fn < 4; ++fn)
        bf[fn] = *(const short8*)&Bs[wc + fn * 16 + l15][ks * 32 + g * 8];
#pragma unroll
      for (int fm = 0; fm < 4; ++fm)
#pragma unroll
        for (int fn = 0; fn < 4; ++fn)
          acc[fm][fn] = __builtin_amdgcn_mfma_f32_16x16x32_bf16(
              af[fm], bf[fn], acc[fm][fn], 0, 0, 0);
    }
    if (kt < 7) __syncthreads();
  }
#pragma unroll
  for (int fn = 0; fn < 4; ++fn) {
    int col = nt * 128 + wc + fn * 16 + l15;
    float bs = bias[col];
#pragma unroll
    for (int fm = 0; fm < 4; ++fm) {
      int row = mt * 128 + wr + fm * 16 + 4 * g;
#pragma unroll
      for (int r = 0; r < 4; ++r)
        Cf[(size_t)(row + r) * 512 + col] = acc[fm][fn][r] + bs;
    }
  }
}

// ---------- fused relative attention ----------
// 1D grid 1024 (XCD-swizzled), 256 threads (4 waves x 16 Q-rows).
// Circular 128-row window; 5-fragment window trim; wave-uniform f16-packed
// shift; no-max softmax; probs in the dead half with XOR-swizzled cols
// (write col' = (fn^g)*16+l15, read granule ^ (l15>>2)<<1) -> conflict-free.
// aqv derived in-register from aqu + (v-u).
__global__ __launch_bounds__(256, 3) void attn_kernel(
    const unsigned short* __restrict__ QU,  // (B*T,512) bf16 = q+bq+u
    const unsigned short* __restrict__ K,   // (B*T,512) bf16
    const unsigned short* __restrict__ Vt,  // [b][h][d][s] bf16
    const unsigned short* __restrict__ P,   // (2047,512) bf16
    const float* __restrict__ uvec,         // (8,64) flat
    const float* __restrict__ vvec,         // (8,64) flat
    unsigned short* __restrict__ O) {       // (B*T,512) bf16
  __shared__ __align__(16) unsigned short k_s[64][72];
  __shared__ __align__(16) unsigned short vt_s[64][72];
  __shared__ __align__(16) unsigned short win_s[128 * 72];

  // XCD swizzle: 1024 blocks = 8 XCDs x 128 contiguous (b,h) groups
  int pid = blockIdx.x;
  int wid = (pid & 7) * 128 + (pid >> 3);
  int tt = wid & 15, h = (wid >> 4) & 7, b = wid >> 7;
  int t0 = tt * 64;
  int tid = threadIdx.x, lane = tid & 63, wave = tid >> 6;
  int lr = tid >> 2, lc = (tid & 3) << 4;
  int l15 = lane & 15, g = lane >> 4;
  int w16 = wave * 16;
  int C = 3 - wave;

  // Q fragments from global; aqv = aqu + (v-u) computed in registers
  short8 aqu[2], aqv[2];
  {
    size_t qoff = (size_t)(b * 1024 + t0 + w16 + l15) * 512 + h * 64 + g * 8;
    aqu[0] = *(const short8*)(QU + qoff);
    aqu[1] = *(const short8*)(QU + qoff + 32);
    const float* up = uvec + h * 64 + g * 8;
    const float* vp = vvec + h * 64 + g * 8;
#pragma unroll
    for (int ks = 0; ks < 2; ++ks) {
      float4 u0 = *(const float4*)(up + ks * 32);
      float4 u1 = *(const float4*)(up + ks * 32 + 4);
      float4 v0 = *(const float4*)(vp + ks * 32);
      float4 v1 = *(const float4*)(vp + ks * 32 + 4);
      float dv[8] = {v0.x - u0.x, v0.y - u0.y, v0.z - u0.z, v0.w - u0.w,
                     v1.x - u1.x, v1.y - u1.y, v1.z - u1.z, v1.w - u1.w};
      short8 t;
#pragma unroll
      for (int j = 0; j < 8; ++j)
        t[j] = (short)f2bf(bf2f((unsigned short)aqu[ks][j]) + dv[j]);
      aqv[ks] = t;
    }
  }

  const unsigned short* Kbase = K + (size_t)(b * 1024) * 512 + h * 64;
  const unsigned short* Vbase = Vt + (size_t)((b * 8 + h) * 64) * 1024;

  float4v accO[4] = {};
  float l_r[4] = {0.f, 0.f, 0.f, 0.f};

  // -------- prologue: stage tile 0 (K, V^T, full 128-row window) --------
  {
    const unsigned short* kp = Kbase + (size_t)lr * 512 + lc;
    uint4 k0 = *(const uint4*)kp, k1 = *(const uint4*)(kp + 8);
    const unsigned short* vp = Vbase + (size_t)lr * 1024 + lc;
    uint4 v0 = *(const uint4*)vp, v1 = *(const uint4*)(vp + 8);
    int r2 = tid >> 1, c2 = (tid & 1) << 5;
    int ph0 = (tt + 1) & 1;
    int wr = 960 - t0 + r2;                       // in [0,1087], no clamp
    const unsigned short* pp = P + (size_t)wr * 512 + h * 64 + c2;
    uint4 w0v = *(const uint4*)pp,        w1v = *(const uint4*)(pp + 8);
    uint4 w2v = *(const uint4*)(pp + 16), w3v = *(const uint4*)(pp + 24);
    *(uint4*)&k_s[lr][lc]      = k0; *(uint4*)&k_s[lr][lc + 8]  = k1;
    *(uint4*)&vt_s[lr][lc]     = v0; *(uint4*)&vt_s[lr][lc + 8] = v1;
    unsigned short* dp = &win_s[(r2 ^ (ph0 << 6)) * 72 + c2];
    *(uint4*)dp        = w0v; *(uint4*)(dp + 8)  = w1v;
    *(uint4*)(dp + 16) = w2v; *(uint4*)(dp + 24) = w3v;
  }
  __syncthreads();

  uint4 pk0, pk1, pv0, pv1, pw0, pw1;
  for (int st = 0; st < 16; ++st) {
    int ph = (st + tt + 1) & 1;
    // issue next tile's global loads (latency hides under compute)
    if (st < 15) {
      int s0n = (st + 1) * 64;
      const unsigned short* kp = Kbase + (size_t)(s0n + lr) * 512 + lc;
      pk0 = *(const uint4*)kp; pk1 = *(const uint4*)(kp + 8);
      const unsigned short* vp = Vbase + (size_t)lr * 1024 + s0n + lc;
      pv0 = *(const uint4*)vp; pv1 = *(const uint4*)(vp + 8);
      int wr = 64 * st - t0 + 1088 + lr; if (wr > 2046) wr = 2046;
      const unsigned short* pp = P + (size_t)wr * 512 + h * 64 + lc;
      pw0 = *(const uint4*)pp; pw1 = *(const uint4*)(pp + 8);
    }

    // content scores (64x64, A=QU) + the 5 needed window fragments (A=QV)
    float4v accS[4] = {}; float4v accP[5] = {};
#pragma unroll
    for (int ks = 0; ks < 2; ++ks) {
#pragma unroll
      for (int fn = 0; fn < 4; ++fn) {
        short8 bk = *(const short8*)&k_s[fn * 16 + l15][ks * 32 + g * 8];
        accS[fn] = __builtin_amdgcn_mfma_f32_16x16x32_bf16(aqu[ks], bk, accS[fn], 0, 0, 0);
      }
#pragma unroll
      for (int k = 0; k < 5; ++k) {
        int fi = (k + C) ^ (ph << 2);   // physical frag of logical C+k
        short8 bp = *(const short8*)&win_s[(fi * 16 + l15) * 72 + ks * 32 + g * 8];
        accP[k] = __builtin_amdgcn_mfma_f32_16x16x32_bf16(aqv[ks], bp, accP[k], 0, 0, 0);
      }
    }

    // relative shift via packed-f16 lane rotation (wave-uniform)
#pragma unroll
    for (int r = 0; r < 4; ++r) {
      int W0 = pk2h(accP[0][r], accP[1][r]);
      int W1 = pk2h(accP[1][r], accP[2][r]);
      int W2 = pk2h(accP[2][r], accP[3][r]);
      int W3 = pk2h(accP[3][r], accP[4][r]);
      int srcLane = (lane & 48) | ((l15 - 4 * g - r - 1) & 15);
      int carry = (l15 >= 4 * g + r + 1);
      int x0 = __shfl(W0, srcLane), x1 = __shfl(W1, srcLane);
      int x2 = __shfl(W2, srcLane), x3 = __shfl(W3, srcLane);
      int wa = carry ? x1 : x0;
      int wb = carry ? x3 : x2;
      accS[0][r] = (accS[0][r] + h_lo(wa)) * 0.125f;
      accS[1][r] = (accS[1][r] + h_hi(wa)) * 0.125f;
      accS[2][r] = (accS[2][r] + h_lo(wb)) * 0.125f;
      accS[3][r] = (accS[3][r] + h_hi(wb)) * 0.125f;
    }

    __syncthreads();     // B3: all waves done reading window/k_s

    // no-max softmax: e = exp(s - 8); probs -> dead half, cols XOR'd by g
    int pbase = (ph << 6) + w16;
#pragma unroll
    for (int r = 0; r < 4; ++r) {
      float rs = 0.f;
#pragma unroll
      for (int fn = 0; fn < 4; ++fn) {
        float e = __expf(accS[fn][r] - 8.0f);
        win_s[(pbase + 4 * g + r) * 72 + ((fn ^ g) * 16 + l15)] = f2bf(e);
        rs += e;
      }
      l_r[r] += rs;
    }

    // PV: accO += P @ V (A-frag: own probs rows, swizzle-read; B: vt_s)
#pragma unroll
    for (int ks = 0; ks < 2; ++ks) {
      int cks = (ks * 32 + g * 8) ^ ((l15 >> 2) << 4);
      short8 ap = *(const short8*)&win_s[(pbase + l15) * 72 + cks];
#pragma unroll
      for (int fn = 0; fn < 4; ++fn) {
        short8 bv = *(const short8*)&vt_s[fn * 16 + l15][ks * 32 + g * 8];
        accO[fn] = __builtin_amdgcn_mfma_f32_16x16x32_bf16(ap, bv, accO[fn], 0, 0, 0);
      }
    }

    if (st < 15) {
      __syncthreads();   // B1: probs + vt_s reads done everywhere
      // STORET: K, V^T, and the 64 NEW window rows into the dead half
      *(uint4*)&k_s[lr][lc]      = pk0; *(uint4*)&k_s[lr][lc + 8]  = pk1;
      *(uint4*)&vt_s[lr][lc]     = pv0; *(uint4*)&vt_s[lr][lc + 8] = pv1;
      unsigned short* dp = &win_s[(lr + (ph << 6)) * 72 + lc];
      *(uint4*)dp = pw0; *(uint4*)(dp + 8) = pw1;
      __syncthreads();   // B2: staging visible
    }
  }

  // epilogue: reduce l across the 16-lane row group, then O / l -> bf16
  float rinv[4];
#pragma unroll
  for (int r = 0; r < 4; ++r) {
    float l = l_r[r];
    l += __shfl_xor(l, 1); l += __shfl_xor(l, 2);
    l += __shfl_xor(l, 4); l += __shfl_xor(l, 8);
    rinv[r] = 1.0f / l;
  }
#pragma unroll
  for (int fn = 0; fn < 4; ++fn) {
    int dcol = fn * 16 + l15;
#pragma unroll
    for (int r = 0; r < 4; ++r) {
      int row = t0 + w16 + 4 * g + r;
      float o = accO[fn][r] * rinv[r];
      O[(size_t)(b * 1024 + row) * 512 + h * 64 + dcol] = f2bf(o);
    }
  }
}

// ---------- host ----------
extern "C" void kernel_launch(void* const* d_in, const int* in_sizes, int n_in,
                              void* d_out, int out_size, void* d_ws, size_t ws_size,
                              hipStream_t stream) {
  const float* x       = (const float*)d_in[0];
  const float* pos_emb = (const float*)d_in[1];
  const float* Wq      = (const float*)d_in[2];
  const float* bq      = (const float*)d_in[3];
  const float* Wk      = (const float*)d_in[4];
  const float* Wv      = (const float*)d_in[5];
  const float* Wp      = (const float*)d_in[6];
  const float* Wo      = (const float*)d_in[7];
  const float* bo      = (const float*)d_in[8];
  const float* u       = (const float*)d_in[9];
  const float* v       = (const float*)d_in[10];

  char* ws = (char*)d_ws;
  unsigned short* xb   = (unsigned short*)ws; ws += (size_t)8192 * 512 * 2;
  unsigned short* peb  = (unsigned short*)ws; ws += (size_t)2048 * 512 * 2;
  unsigned short* wqkv = (unsigned short*)ws; ws += (size_t)5 * 512 * 512 * 2;
  unsigned short* qub  = (unsigned short*)ws; ws += (size_t)8192 * 512 * 2;
  unsigned short* kb   = (unsigned short*)ws; ws += (size_t)8192 * 512 * 2;
  unsigned short* vtb  = (unsigned short*)ws; ws += (size_t)8192 * 512 * 2;
  unsigned short* pb   = (unsigned short*)ws; ws += (size_t)2048 * 512 * 2;
  unsigned short* attb = (unsigned short*)ws; ws += (size_t)8192 * 512 * 2;

  cvt_bf16_kernel<<<4096, 256, 0, stream>>>(x, xb, 1048576);
  cvt_bf16_kernel<<<1024, 256, 0, stream>>>(pos_emb, peb, 262016);
  transpose_cvt5_kernel<<<dim3(64, 5), 256, 0, stream>>>(Wq, Wk, Wv, Wp, Wo, wqkv);
  unsigned short* wpt_p = wqkv + (size_t)3 * 262144;
  unsigned short* wot_p = wqkv + (size_t)4 * 262144;

  qkv_gemm128<<<dim3(64, 13), 256, 0, stream>>>(xb, wqkv, bq, u,
                                                qub, kb, vtb,
                                                peb, wpt_p, pb);

  attn_kernel<<<1024, 256, 0, stream>>>(qub, kb, vtb, pb, u, v, attb);

  gemm128f<<<dim3(64, 4), 256, 0, stream>>>(attb, wot_p, bo, (float*)d_out);
}